// Round 3
// baseline (195.326 us; speedup 1.0000x reference)
//
#include <hip/hip_runtime.h>

#define NN 100000
#define NE 1250000
#define D 64

// ---------------------------------------------------------------------------
// k_rowptr: dst sorted ascending -> row_ptr[v] = first edge with dst >= v.
// ---------------------------------------------------------------------------
__global__ __launch_bounds__(256) void k_rowptr(const int* __restrict__ dst,
                                                int* __restrict__ row_ptr) {
    const int i = blockIdx.x * 256 + threadIdx.x;
    if (i >= NE) return;
    const int d = dst[i];
    const int prev = (i == 0) ? -1 : dst[i - 1];
    for (int v = prev + 1; v <= d; ++v) row_ptr[v] = i;
    if (i == NE - 1) {
        for (int v = d + 1; v <= NN; ++v) row_ptr[v] = NE;
    }
}

// ---------------------------------------------------------------------------
// k_neigh: CSR mean aggregation, float4 gather.
// Lane layout: sub = lane>>4 (edge slot 0..3), q = lane&15 (float4 within row).
// One wave per node; 16 edges per batch -> ~1 memory round-trip at deg~12.5.
// Cross-slot reduce via 2 shfl_xor steps. Writes normalized h (no atomics).
// ---------------------------------------------------------------------------
__global__ __launch_bounds__(256) void k_neigh(const float* __restrict__ x,
                                               const int* __restrict__ src,
                                               const int* __restrict__ row_ptr,
                                               float* __restrict__ h) {
    const int tid  = threadIdx.x;
    const int lane = tid & 63;
    const int sub  = lane >> 4;
    const int q    = lane & 15;
    const int w    = tid >> 6;
    const int v    = blockIdx.x * 4 + w;
    if (v >= NN) return;
    const int lo = row_ptr[v];
    const int hi = row_ptr[v + 1];

    float4 acc = make_float4(0.f, 0.f, 0.f, 0.f);
    for (int e0 = lo + sub; e0 < hi; e0 += 16) {
        float4 r[4];
        // issue all loads first (clamped address for inactive slots -> L1 hit)
        #pragma unroll
        for (int j = 0; j < 4; ++j) {
            const int e = e0 + j * 4;
            const int ec = (e < hi) ? e : lo;
            r[j] = *(const float4*)(x + (size_t)src[ec] * D + q * 4);
        }
        #pragma unroll
        for (int j = 0; j < 4; ++j) {
            const int e = e0 + j * 4;
            if (e < hi) {
                acc.x += r[j].x; acc.y += r[j].y; acc.z += r[j].z; acc.w += r[j].w;
            }
        }
    }
    // reduce the 4 edge slots (lanes differing in bits 4-5)
    #pragma unroll
    for (int off = 16; off < 64; off <<= 1) {
        acc.x += __shfl_xor(acc.x, off);
        acc.y += __shfl_xor(acc.y, off);
        acc.z += __shfl_xor(acc.z, off);
        acc.w += __shfl_xor(acc.w, off);
    }
    if (sub == 0) {
        const float inv = (hi > lo) ? 1.0f / (float)(hi - lo) : 0.0f;
        float4 o;
        o.x = acc.x * inv; o.y = acc.y * inv; o.z = acc.z * inv; o.w = acc.w * inv;
        *(float4*)(h + (size_t)v * D + q * 4) = o;
    }
}

// ---------------------------------------------------------------------------
// k_out: out[n][j] = b[j] + sum_k x[n][k]*Ws[k][j] + h[n][k]*Wn[k][j].
// Lane j holds W columns in VGPRs, PINNED via empty inline-asm so the
// compiler cannot re-materialize the loads inside the node loop (round-2
// failure mode: VGPR_Count=68 proved the weights were reloaded per node).
// Node rows are wave-uniform -> scalar loads feed the SGPR operand of
// v_fma_f32. Zero LDS (broadcast LDS reads pay the full 64-lane return-bus
// cost; the scalar path is the only free per-k broadcast).
// ---------------------------------------------------------------------------
__global__ __launch_bounds__(256, 3) void k_out(const float* __restrict__ x,
                                                const float* __restrict__ h,
                                                const float* __restrict__ Wself,
                                                const float* __restrict__ Wneigh,
                                                const float* __restrict__ b,
                                                float* __restrict__ out) {
    const int tid = threadIdx.x;
    const int lane = tid & 63;
    const int w = tid >> 6;

    float ws[D], wn[D];
    #pragma unroll
    for (int k = 0; k < D; ++k) ws[k] = Wself[k * D + lane];
    #pragma unroll
    for (int k = 0; k < D; ++k) wn[k] = Wneigh[k * D + lane];
    // Opaque register barrier: forces ws/wn to live in 128 distinct VGPRs
    // across the node loop; downstream FMAs must read the asm's output.
    #pragma unroll
    for (int k = 0; k < D; ++k) {
        asm volatile("" : "+v"(ws[k]));
        asm volatile("" : "+v"(wn[k]));
    }
    const float bv = b[lane];

    const int wave0 = blockIdx.x * 4 + w;
    const int nwaves = gridDim.x * 4;
    for (int n = wave0; n < NN; n += nwaves) {
        const int nu = __builtin_amdgcn_readfirstlane(n);
        const float* __restrict__ xr = x + (size_t)nu * D;
        const float* __restrict__ hr = h + (size_t)nu * D;
        float acc = bv;
        #pragma unroll
        for (int k = 0; k < D; ++k) {
            acc = fmaf(xr[k], ws[k], acc);   // SGPR (s_load) * pinned VGPR
            acc = fmaf(hr[k], wn[k], acc);
        }
        out[(size_t)nu * D + lane] = acc;
    }
}

extern "C" void kernel_launch(void* const* d_in, const int* in_sizes, int n_in,
                              void* d_out, int out_size, void* d_ws, size_t ws_size,
                              hipStream_t stream) {
    const float* x      = (const float*)d_in[0];
    const float* Wself  = (const float*)d_in[1];
    const float* Wneigh = (const float*)d_in[2];
    const float* b      = (const float*)d_in[3];
    const int*   src    = (const int*)d_in[4];
    const int*   dst    = (const int*)d_in[5];
    float* out = (float*)d_out;

    float* h       = (float*)d_ws;                 // [NN * D]
    int*   row_ptr = (int*)(h + (size_t)NN * D);   // [NN + 1]

    k_rowptr<<<(NE + 255) / 256, 256, 0, stream>>>(dst, row_ptr);
    k_neigh<<<(NN + 3) / 4, 256, 0, stream>>>(x, src, row_ptr, h);
    // grid-stride: 768 blocks = 3 blocks/CU; ~33 nodes/wave amortizes the
    // one-time 128-VGPR weight stage.
    k_out<<<768, 256, 0, stream>>>(x, h, Wself, Wneigh, b, out);
}

// Round 4
// 182.479 us; speedup vs baseline: 1.0704x; 1.0704x over previous
//
#include <hip/hip_runtime.h>

#define NN 100000
#define NE 1250000
#define D 64
#define NTILE 1563              // ceil(NN/64)
#define NWID (NTILE * 2)        // tiles x 2 j-halves

// ---------------------------------------------------------------------------
// k_rowptr: dst sorted ascending -> row_ptr[v] = first edge with dst >= v.
// ---------------------------------------------------------------------------
__global__ __launch_bounds__(256) void k_rowptr(const int* __restrict__ dst,
                                                int* __restrict__ row_ptr) {
    const int i = blockIdx.x * 256 + threadIdx.x;
    if (i >= NE) return;
    const int d = dst[i];
    const int prev = (i == 0) ? -1 : dst[i - 1];
    for (int v = prev + 1; v <= d; ++v) row_ptr[v] = i;
    if (i == NE - 1) {
        for (int v = d + 1; v <= NN; ++v) row_ptr[v] = NE;
    }
}

// ---------------------------------------------------------------------------
// k_gemm2: one pass over x computing BOTH
//   z[n][j] = b[j] + sum_k x[n][k] * Wself[k][j]   -> written to d_out
//   y[n][j] =        sum_k x[n][k] * Wneigh[k][j]  -> workspace
// Layout: lane = node (64 nodes per wave), each wave does a 32-wide j-half.
// Accumulators live in VGPRs (loop-carried FMA chains: the allocator cannot
// spill/remat them away — this avoids rounds 2/3's failure). Weight values
// are lane-uniform -> s_load into SGPRs, consumed as the SGPR operand of
// v_fma_f32. Per-lane x loads are dwordx4; the 4x cacheline over-read hits
// L2/L3 only (x is 25.6 MB, L3-resident).
// ---------------------------------------------------------------------------
__global__ __launch_bounds__(256) void k_gemm2(const float* __restrict__ x,
                                               const float* __restrict__ Wself,
                                               const float* __restrict__ Wneigh,
                                               const float* __restrict__ b,
                                               float* __restrict__ z,
                                               float* __restrict__ y) {
    const int lane = threadIdx.x & 63;
    const int wid = __builtin_amdgcn_readfirstlane(blockIdx.x * 4 + (threadIdx.x >> 6));
    if (wid >= NWID) return;
    const int tile = wid >> 1;
    const int j0 = (wid & 1) * 32;

    const int n = tile * 64 + lane;
    const int nc = (n < NN) ? n : (NN - 1);
    const float* __restrict__ xr = x + (size_t)nc * D;

    float accz[32], accy[32];
    #pragma unroll
    for (int j = 0; j < 32; ++j) { accz[j] = 0.0f; accy[j] = 0.0f; }

    #pragma unroll 2
    for (int k4 = 0; k4 < D / 4; ++k4) {
        const float4 xv = *(const float4*)(xr + k4 * 4);   // per-lane 16 B
        const float xk[4] = {xv.x, xv.y, xv.z, xv.w};
        #pragma unroll
        for (int i = 0; i < 4; ++i) {
            const int k = k4 * 4 + i;
            const float* __restrict__ wsr = Wself + k * D + j0;   // uniform
            const float* __restrict__ wnr = Wneigh + k * D + j0;  // uniform
            #pragma unroll
            for (int j = 0; j < 32; ++j) {
                accz[j] = fmaf(xk[i], wsr[j], accz[j]);  // VGPR*SGPR+VGPR
                accy[j] = fmaf(xk[i], wnr[j], accy[j]);
            }
        }
    }

    if (n < NN) {
        float* __restrict__ zo = z + (size_t)n * D + j0;
        float* __restrict__ yo = y + (size_t)n * D + j0;
        #pragma unroll
        for (int g = 0; g < 8; ++g) {
            float4 vz, vy;
            vz.x = accz[g * 4 + 0] + b[j0 + g * 4 + 0];
            vz.y = accz[g * 4 + 1] + b[j0 + g * 4 + 1];
            vz.z = accz[g * 4 + 2] + b[j0 + g * 4 + 2];
            vz.w = accz[g * 4 + 3] + b[j0 + g * 4 + 3];
            vy.x = accy[g * 4 + 0];
            vy.y = accy[g * 4 + 1];
            vy.z = accy[g * 4 + 2];
            vy.w = accy[g * 4 + 3];
            *(float4*)(zo + g * 4) = vz;
            *(float4*)(yo + g * 4) = vy;
        }
    }
}

// ---------------------------------------------------------------------------
// k_aggr: out[v][:] = z[v][:] + mean_{u in N(v)} y[u][:]
// (z already sits in d_out from k_gemm2; RMW fuse). One wave per node;
// lane = (edge slot sub 0..3, float4 q 0..15); 16 edges in flight per batch.
// Cross-slot reduce via 2 shfl_xor steps.
// ---------------------------------------------------------------------------
__global__ __launch_bounds__(256) void k_aggr(const float* __restrict__ y,
                                              const int* __restrict__ src,
                                              const int* __restrict__ row_ptr,
                                              float* __restrict__ out) {
    const int tid  = threadIdx.x;
    const int lane = tid & 63;
    const int sub  = lane >> 4;
    const int q    = lane & 15;
    const int v    = blockIdx.x * 4 + (tid >> 6);
    if (v >= NN) return;
    const int lo = row_ptr[v];
    const int hi = row_ptr[v + 1];

    float4 acc = make_float4(0.f, 0.f, 0.f, 0.f);
    for (int e0 = lo + sub; e0 < hi; e0 += 16) {
        float4 r[4];
        #pragma unroll
        for (int j = 0; j < 4; ++j) {
            const int e = e0 + j * 4;
            const int ec = (e < hi) ? e : lo;     // clamped: same line, L1-hit
            r[j] = *(const float4*)(y + (size_t)src[ec] * D + q * 4);
        }
        #pragma unroll
        for (int j = 0; j < 4; ++j) {
            const int e = e0 + j * 4;
            if (e < hi) {
                acc.x += r[j].x; acc.y += r[j].y; acc.z += r[j].z; acc.w += r[j].w;
            }
        }
    }
    #pragma unroll
    for (int off = 16; off < 64; off <<= 1) {
        acc.x += __shfl_xor(acc.x, off);
        acc.y += __shfl_xor(acc.y, off);
        acc.z += __shfl_xor(acc.z, off);
        acc.w += __shfl_xor(acc.w, off);
    }
    if (sub == 0) {
        const float inv = (hi > lo) ? 1.0f / (float)(hi - lo) : 0.0f;
        float4* op = (float4*)(out + (size_t)v * D + q * 4);
        float4 o = *op;   // z from k_gemm2
        o.x += acc.x * inv; o.y += acc.y * inv;
        o.z += acc.z * inv; o.w += acc.w * inv;
        *op = o;
    }
}

extern "C" void kernel_launch(void* const* d_in, const int* in_sizes, int n_in,
                              void* d_out, int out_size, void* d_ws, size_t ws_size,
                              hipStream_t stream) {
    const float* x      = (const float*)d_in[0];
    const float* Wself  = (const float*)d_in[1];
    const float* Wneigh = (const float*)d_in[2];
    const float* b      = (const float*)d_in[3];
    const int*   src    = (const int*)d_in[4];
    const int*   dst    = (const int*)d_in[5];
    float* out = (float*)d_out;

    float* y       = (float*)d_ws;                 // [NN * D]
    int*   row_ptr = (int*)(y + (size_t)NN * D);   // [NN + 1]

    k_rowptr<<<(NE + 255) / 256, 256, 0, stream>>>(dst, row_ptr);
    k_gemm2<<<(NWID + 3) / 4, 256, 0, stream>>>(x, Wself, Wneigh, b, out, y);
    k_aggr<<<(NN + 3) / 4, 256, 0, stream>>>(y, src, row_ptr, out);
}

// Round 5
// 172.127 us; speedup vs baseline: 1.1348x; 1.0601x over previous
//
#include <hip/hip_runtime.h>

#define NN 100000
#define NE 1250000
#define D 64
#define NTILE 1563              // ceil(NN/64) node tiles
#define NWID (NTILE * 4)        // x4 tile types: (Wself|Wneigh) x (j-half)

// ---------------------------------------------------------------------------
// k_rowptr: dst sorted ascending -> row_ptr[v] = first edge with dst >= v.
// ---------------------------------------------------------------------------
__global__ __launch_bounds__(256) void k_rowptr(const int* __restrict__ dst,
                                                int* __restrict__ row_ptr) {
    const int i = blockIdx.x * 256 + threadIdx.x;
    if (i >= NE) return;
    const int d = dst[i];
    const int prev = (i == 0) ? -1 : dst[i - 1];
    for (int v = prev + 1; v <= d; ++v) row_ptr[v] = i;
    if (i == NE - 1) {
        for (int v = d + 1; v <= NN; ++v) row_ptr[v] = NE;
    }
}

// ---------------------------------------------------------------------------
// k_gemm: each wave computes ONE of 4 tile types for a 64-node tile:
//   sel 0: z[:, 0:32]  = x@Wself[:,0:32]  + b   -> d_out
//   sel 1: z[:,32:64]  = x@Wself[:,32:64] + b   -> d_out
//   sel 2: y[:, 0:32]  = x@Wneigh[:,0:32]       -> ws
//   sel 3: y[:,32:64]  = x@Wneigh[:,32:64]      -> ws
// lane = node. acc[32] per thread — round 4 proved the allocator keeps ~52
// VGPRs live but spills at 64+acc; 32 fits with headroom (spill fix).
// Weight rows are wave-uniform -> s_load (SGPR operand of v_fma_f32).
// x row: per-lane float4 loads; 64B lines reused across 4 consecutive k4
// iterations (L1), misses absorbed by L3 (x = 25.6 MB).
// ---------------------------------------------------------------------------
__global__ __launch_bounds__(256) void k_gemm(const float* __restrict__ x,
                                              const float* __restrict__ Wself,
                                              const float* __restrict__ Wneigh,
                                              const float* __restrict__ b,
                                              float* __restrict__ z,
                                              float* __restrict__ y) {
    const int lane = threadIdx.x & 63;
    const int wid = __builtin_amdgcn_readfirstlane(blockIdx.x * 4 + (threadIdx.x >> 6));
    if (wid >= NWID) return;
    const int tile = wid >> 2;
    const int sel = wid & 3;
    const int jh = (sel & 1) * 32;
    const float* __restrict__ W = (sel & 2) ? Wneigh : Wself;

    const int n = tile * 64 + lane;
    const int nc = (n < NN) ? n : (NN - 1);
    const float* __restrict__ xr = x + (size_t)nc * D;

    float acc[32];
    #pragma unroll
    for (int j = 0; j < 32; ++j) acc[j] = 0.0f;

    #pragma unroll 2
    for (int k4 = 0; k4 < D / 4; ++k4) {
        const float4 xv = *(const float4*)(xr + k4 * 4);   // per-lane 16 B
        const float xk[4] = {xv.x, xv.y, xv.z, xv.w};
        #pragma unroll
        for (int i = 0; i < 4; ++i) {
            const float* __restrict__ wr = W + (k4 * 4 + i) * D + jh;  // uniform
            #pragma unroll
            for (int j = 0; j < 32; ++j) {
                acc[j] = fmaf(xk[i], wr[j], acc[j]);  // VGPR * SGPR + VGPR
            }
        }
    }

    if (n < NN) {
        if (sel & 2) {
            float* __restrict__ yo = y + (size_t)n * D + jh;
            #pragma unroll
            for (int g = 0; g < 8; ++g) {
                float4 v;
                v.x = acc[g * 4 + 0]; v.y = acc[g * 4 + 1];
                v.z = acc[g * 4 + 2]; v.w = acc[g * 4 + 3];
                *(float4*)(yo + g * 4) = v;
            }
        } else {
            float* __restrict__ zo = z + (size_t)n * D + jh;
            const float* __restrict__ br = b + jh;   // uniform
            #pragma unroll
            for (int g = 0; g < 8; ++g) {
                float4 v;
                v.x = acc[g * 4 + 0] + br[g * 4 + 0];
                v.y = acc[g * 4 + 1] + br[g * 4 + 1];
                v.z = acc[g * 4 + 2] + br[g * 4 + 2];
                v.w = acc[g * 4 + 3] + br[g * 4 + 3];
                *(float4*)(zo + g * 4) = v;
            }
        }
    }
}

// ---------------------------------------------------------------------------
// k_aggr: out[v][:] = z[v][:] + mean_{u in N(v)} y[u][:]
// (z already in d_out; RMW fuse). One wave per node; lane = (edge slot 0..3,
// float4 q 0..15); 16 edges in flight. Cross-slot reduce via 2 shfl_xor.
// ---------------------------------------------------------------------------
__global__ __launch_bounds__(256) void k_aggr(const float* __restrict__ y,
                                              const int* __restrict__ src,
                                              const int* __restrict__ row_ptr,
                                              float* __restrict__ out) {
    const int tid  = threadIdx.x;
    const int lane = tid & 63;
    const int sub  = lane >> 4;
    const int q    = lane & 15;
    const int v    = blockIdx.x * 4 + (tid >> 6);
    if (v >= NN) return;
    const int lo = row_ptr[v];
    const int hi = row_ptr[v + 1];

    float4 acc = make_float4(0.f, 0.f, 0.f, 0.f);
    for (int e0 = lo + sub; e0 < hi; e0 += 16) {
        float4 r[4];
        #pragma unroll
        for (int j = 0; j < 4; ++j) {
            const int e = e0 + j * 4;
            const int ec = (e < hi) ? e : lo;     // clamp: row re-hit, L1
            r[j] = *(const float4*)(y + (size_t)src[ec] * D + q * 4);
        }
        #pragma unroll
        for (int j = 0; j < 4; ++j) {
            const int e = e0 + j * 4;
            if (e < hi) {
                acc.x += r[j].x; acc.y += r[j].y; acc.z += r[j].z; acc.w += r[j].w;
            }
        }
    }
    #pragma unroll
    for (int off = 16; off < 64; off <<= 1) {
        acc.x += __shfl_xor(acc.x, off);
        acc.y += __shfl_xor(acc.y, off);
        acc.z += __shfl_xor(acc.z, off);
        acc.w += __shfl_xor(acc.w, off);
    }
    if (sub == 0) {
        const float inv = (hi > lo) ? 1.0f / (float)(hi - lo) : 0.0f;
        float4* op = (float4*)(out + (size_t)v * D + q * 4);
        float4 o = *op;   // z from k_gemm
        o.x += acc.x * inv; o.y += acc.y * inv;
        o.z += acc.z * inv; o.w += acc.w * inv;
        *op = o;
    }
}

extern "C" void kernel_launch(void* const* d_in, const int* in_sizes, int n_in,
                              void* d_out, int out_size, void* d_ws, size_t ws_size,
                              hipStream_t stream) {
    const float* x      = (const float*)d_in[0];
    const float* Wself  = (const float*)d_in[1];
    const float* Wneigh = (const float*)d_in[2];
    const float* b      = (const float*)d_in[3];
    const int*   src    = (const int*)d_in[4];
    const int*   dst    = (const int*)d_in[5];
    float* out = (float*)d_out;

    float* y       = (float*)d_ws;                 // [NN * D]
    int*   row_ptr = (int*)(y + (size_t)NN * D);   // [NN + 1]

    k_rowptr<<<(NE + 255) / 256, 256, 0, stream>>>(dst, row_ptr);
    k_gemm<<<(NWID + 3) / 4, 256, 0, stream>>>(x, Wself, Wneigh, b, out, y);
    k_aggr<<<(NN + 3) / 4, 256, 0, stream>>>(y, src, row_ptr, out);
}

// Round 6
// 157.691 us; speedup vs baseline: 1.2387x; 1.0915x over previous
//
#include <hip/hip_runtime.h>
#include <hip/hip_fp16.h>

#define NN 100000
#define NE 1250000
#define D 64
#define NTILE 1563              // ceil(NN/64) node tiles
#define NWID (NTILE * 4)        // x4 tile types: (Wself|Wneigh) x (j-half)

__device__ inline float2 cvt2(unsigned u) {
    __half2 h = __builtin_bit_cast(__half2, u);
    return __half22float2(h);
}
__device__ inline unsigned pack2(float a, float b) {
    __half2 h = __floats2half2_rn(a, b);
    return __builtin_bit_cast(unsigned, h);
}

// ---------------------------------------------------------------------------
// k_rowptr: dst sorted ascending -> row_ptr[v] = first edge with dst >= v.
// ---------------------------------------------------------------------------
__global__ __launch_bounds__(256) void k_rowptr(const int* __restrict__ dst,
                                                int* __restrict__ row_ptr) {
    const int i = blockIdx.x * 256 + threadIdx.x;
    if (i >= NE) return;
    const int d = dst[i];
    const int prev = (i == 0) ? -1 : dst[i - 1];
    for (int v = prev + 1; v <= d; ++v) row_ptr[v] = i;
    if (i == NE - 1) {
        for (int v = d + 1; v <= NN; ++v) row_ptr[v] = NE;
    }
}

// ---------------------------------------------------------------------------
// k_gemm: each wave computes ONE of 4 tile types for a 64-node tile:
//   sel 0/1: z[:, jh:jh+32] = x@Wself[:,jh:jh+32] + b -> d_out (fp32)
//   sel 2/3: y[:, jh:jh+32] = x@Wneigh[:,jh:jh+32]    -> ws (FP16: the
//            aggregation gather is per-XCD compulsory-miss bound, so halving
//            row bytes halves its HBM/L3 fetch — round-5 counters)
// lane = node; acc[32] in VGPRs (round 4 proved 64 spills, 32 fits).
// Weight rows are wave-uniform -> s_load, SGPR operand of v_fma_f32.
// ---------------------------------------------------------------------------
__global__ __launch_bounds__(256) void k_gemm(const float* __restrict__ x,
                                              const float* __restrict__ Wself,
                                              const float* __restrict__ Wneigh,
                                              const float* __restrict__ b,
                                              float* __restrict__ z,
                                              __half* __restrict__ y) {
    const int lane = threadIdx.x & 63;
    const int wid = __builtin_amdgcn_readfirstlane(blockIdx.x * 4 + (threadIdx.x >> 6));
    if (wid >= NWID) return;
    const int tile = wid >> 2;
    const int sel = wid & 3;
    const int jh = (sel & 1) * 32;
    const float* __restrict__ W = (sel & 2) ? Wneigh : Wself;

    const int n = tile * 64 + lane;
    const int nc = (n < NN) ? n : (NN - 1);
    const float* __restrict__ xr = x + (size_t)nc * D;

    float acc[32];
    #pragma unroll
    for (int j = 0; j < 32; ++j) acc[j] = 0.0f;

    #pragma unroll 2
    for (int k4 = 0; k4 < D / 4; ++k4) {
        const float4 xv = *(const float4*)(xr + k4 * 4);   // per-lane 16 B
        const float xk[4] = {xv.x, xv.y, xv.z, xv.w};
        #pragma unroll
        for (int i = 0; i < 4; ++i) {
            const float* __restrict__ wr = W + (k4 * 4 + i) * D + jh;  // uniform
            #pragma unroll
            for (int j = 0; j < 32; ++j) {
                acc[j] = fmaf(xk[i], wr[j], acc[j]);  // VGPR * SGPR + VGPR
            }
        }
    }

    if (n < NN) {
        if (sel & 2) {
            // pack 32 fp32 -> 32 fp16 (64 B) and store as 4 x uint4
            unsigned p[16];
            #pragma unroll
            for (int g = 0; g < 16; ++g) p[g] = pack2(acc[2 * g], acc[2 * g + 1]);
            uint4* __restrict__ yo = (uint4*)(y + (size_t)n * D + jh);
            #pragma unroll
            for (int g = 0; g < 4; ++g) {
                uint4 v;
                v.x = p[4 * g + 0]; v.y = p[4 * g + 1];
                v.z = p[4 * g + 2]; v.w = p[4 * g + 3];
                yo[g] = v;
            }
        } else {
            float* __restrict__ zo = z + (size_t)n * D + jh;
            const float* __restrict__ br = b + jh;   // uniform
            #pragma unroll
            for (int g = 0; g < 8; ++g) {
                float4 v;
                v.x = acc[g * 4 + 0] + br[g * 4 + 0];
                v.y = acc[g * 4 + 1] + br[g * 4 + 1];
                v.z = acc[g * 4 + 2] + br[g * 4 + 2];
                v.w = acc[g * 4 + 3] + br[g * 4 + 3];
                *(float4*)(zo + g * 4) = v;
            }
        }
    }
}

// ---------------------------------------------------------------------------
// k_aggr: out[v][:] = z[v][:] + mean_{u in N(v)} y_fp16[u][:]
// (z already in d_out; RMW fuse). One wave per node. fp16 row = 128 B =
// one cache line: sub = lane>>3 (8 edge slots/instr), q = lane&7 (16 B of
// halves each). 4 loads/batch -> 32 edge rows in flight. fp32 accumulate;
// cross-slot reduce = 3 shfl_xor steps; lanes 0..7 write 256 B coalesced.
// ---------------------------------------------------------------------------
__global__ __launch_bounds__(256) void k_aggr(const __half* __restrict__ y,
                                              const int* __restrict__ src,
                                              const int* __restrict__ row_ptr,
                                              float* __restrict__ out) {
    const int tid  = threadIdx.x;
    const int lane = tid & 63;
    const int sub  = lane >> 3;
    const int q    = lane & 7;
    const int v    = __builtin_amdgcn_readfirstlane(blockIdx.x * 4 + (tid >> 6));
    if (v >= NN) return;
    const int lo = row_ptr[v];
    const int hi = row_ptr[v + 1];

    float acc[8];
    #pragma unroll
    for (int i = 0; i < 8; ++i) acc[i] = 0.0f;

    for (int e0 = lo; e0 < hi; e0 += 32) {
        uint4 r[4];
        #pragma unroll
        for (int j = 0; j < 4; ++j) {
            const int e = e0 + j * 8 + sub;
            const int ec = (e < hi) ? e : lo;     // clamp: line re-hit, L1
            r[j] = *(const uint4*)(y + (size_t)src[ec] * D + q * 8);
        }
        #pragma unroll
        for (int j = 0; j < 4; ++j) {
            const int e = e0 + j * 8 + sub;
            if (e < hi) {
                const float2 f0 = cvt2(r[j].x), f1 = cvt2(r[j].y);
                const float2 f2 = cvt2(r[j].z), f3 = cvt2(r[j].w);
                acc[0] += f0.x; acc[1] += f0.y;
                acc[2] += f1.x; acc[3] += f1.y;
                acc[4] += f2.x; acc[5] += f2.y;
                acc[6] += f3.x; acc[7] += f3.y;
            }
        }
    }
    #pragma unroll
    for (int off = 8; off < 64; off <<= 1) {
        #pragma unroll
        for (int i = 0; i < 8; ++i) acc[i] += __shfl_xor(acc[i], off);
    }
    if (lane < 8) {   // sub == 0: lane q = 0..7 owns cols q*8 .. q*8+7
        const float inv = (hi > lo) ? 1.0f / (float)(hi - lo) : 0.0f;
        float4* op = (float4*)(out + (size_t)v * D + lane * 8);
        float4 o0 = op[0], o1 = op[1];   // z from k_gemm
        o0.x += acc[0] * inv; o0.y += acc[1] * inv;
        o0.z += acc[2] * inv; o0.w += acc[3] * inv;
        o1.x += acc[4] * inv; o1.y += acc[5] * inv;
        o1.z += acc[6] * inv; o1.w += acc[7] * inv;
        op[0] = o0; op[1] = o1;
    }
}

extern "C" void kernel_launch(void* const* d_in, const int* in_sizes, int n_in,
                              void* d_out, int out_size, void* d_ws, size_t ws_size,
                              hipStream_t stream) {
    const float* x      = (const float*)d_in[0];
    const float* Wself  = (const float*)d_in[1];
    const float* Wneigh = (const float*)d_in[2];
    const float* b      = (const float*)d_in[3];
    const int*   src    = (const int*)d_in[4];
    const int*   dst    = (const int*)d_in[5];
    float* out = (float*)d_out;

    __half* y      = (__half*)d_ws;                           // [NN * D] fp16
    int*   row_ptr = (int*)((char*)d_ws + (size_t)NN * D * 2); // [NN + 1]

    k_rowptr<<<(NE + 255) / 256, 256, 0, stream>>>(dst, row_ptr);
    k_gemm<<<(NWID + 3) / 4, 256, 0, stream>>>(x, Wself, Wneigh, b, out, y);
    k_aggr<<<(NN + 3) / 4, 256, 0, stream>>>(y, src, row_ptr, out);
}

// Round 7
// 154.841 us; speedup vs baseline: 1.2615x; 1.0184x over previous
//
#include <hip/hip_runtime.h>
#include <hip/hip_fp16.h>

#define NN 100000
#define NE 1250000
#define D 64
#define NTILE 1563              // ceil(NN/64) node tiles
#define NWID (NTILE * 4)        // x4 tile types: (Wself|Wneigh) x (j-half)

__device__ inline float2 cvt2(unsigned u) {
    __half2 h = __builtin_bit_cast(__half2, u);
    return __half22float2(h);
}
__device__ inline unsigned pack2(float a, float b) {
    __half2 h = __floats2half2_rn(a, b);
    return __builtin_bit_cast(unsigned, h);
}

// ---------------------------------------------------------------------------
// k_rowptr: dst sorted ascending -> row_ptr[v] = first edge with dst >= v.
// ---------------------------------------------------------------------------
__global__ __launch_bounds__(256) void k_rowptr(const int* __restrict__ dst,
                                                int* __restrict__ row_ptr) {
    const int i = blockIdx.x * 256 + threadIdx.x;
    if (i >= NE) return;
    const int d = dst[i];
    const int prev = (i == 0) ? -1 : dst[i - 1];
    for (int v = prev + 1; v <= d; ++v) row_ptr[v] = i;
    if (i == NE - 1) {
        for (int v = d + 1; v <= NN; ++v) row_ptr[v] = NE;
    }
}

// ---------------------------------------------------------------------------
// k_gemm: each wave computes ONE of 4 tile types for a 64-node tile:
//   sel 0/1: z[:, jh:jh+32] = x@Wself[:,jh:jh+32] + b -> d_out (fp32)
//   sel 2/3: y[:, jh:jh+32] = x@Wneigh[:,jh:jh+32]    -> ws (fp16)
// lane = node; acc[32] in VGPRs (64 accs spill — round 4; 32 fits).
// Weight rows are wave-uniform -> s_load, SGPR operand of v_fma_f32.
// ---------------------------------------------------------------------------
__global__ __launch_bounds__(256) void k_gemm(const float* __restrict__ x,
                                              const float* __restrict__ Wself,
                                              const float* __restrict__ Wneigh,
                                              const float* __restrict__ b,
                                              float* __restrict__ z,
                                              __half* __restrict__ y) {
    const int lane = threadIdx.x & 63;
    const int wid = __builtin_amdgcn_readfirstlane(blockIdx.x * 4 + (threadIdx.x >> 6));
    if (wid >= NWID) return;
    const int tile = wid >> 2;
    const int sel = wid & 3;
    const int jh = (sel & 1) * 32;
    const float* __restrict__ W = (sel & 2) ? Wneigh : Wself;

    const int n = tile * 64 + lane;
    const int nc = (n < NN) ? n : (NN - 1);
    const float* __restrict__ xr = x + (size_t)nc * D;

    float acc[32];
    #pragma unroll
    for (int j = 0; j < 32; ++j) acc[j] = 0.0f;

    #pragma unroll 2
    for (int k4 = 0; k4 < D / 4; ++k4) {
        const float4 xv = *(const float4*)(xr + k4 * 4);   // per-lane 16 B
        const float xk[4] = {xv.x, xv.y, xv.z, xv.w};
        #pragma unroll
        for (int i = 0; i < 4; ++i) {
            const float* __restrict__ wr = W + (k4 * 4 + i) * D + jh;  // uniform
            #pragma unroll
            for (int j = 0; j < 32; ++j) {
                acc[j] = fmaf(xk[i], wr[j], acc[j]);  // VGPR * SGPR + VGPR
            }
        }
    }

    if (n < NN) {
        if (sel & 2) {
            unsigned p[16];
            #pragma unroll
            for (int g = 0; g < 16; ++g) p[g] = pack2(acc[2 * g], acc[2 * g + 1]);
            uint4* __restrict__ yo = (uint4*)(y + (size_t)n * D + jh);
            #pragma unroll
            for (int g = 0; g < 4; ++g) {
                uint4 v;
                v.x = p[4 * g + 0]; v.y = p[4 * g + 1];
                v.z = p[4 * g + 2]; v.w = p[4 * g + 3];
                yo[g] = v;
            }
        } else {
            float* __restrict__ zo = z + (size_t)n * D + jh;
            const float* __restrict__ br = b + jh;   // uniform
            #pragma unroll
            for (int g = 0; g < 8; ++g) {
                float4 v;
                v.x = acc[g * 4 + 0] + br[g * 4 + 0];
                v.y = acc[g * 4 + 1] + br[g * 4 + 1];
                v.z = acc[g * 4 + 2] + br[g * 4 + 2];
                v.w = acc[g * 4 + 3] + br[g * 4 + 3];
                *(float4*)(zo + g * 4) = v;
            }
        }
    }
}

// ---------------------------------------------------------------------------
// k_aggr v3: out[v][:] = z[v][:] + mean_{u in N(v)} y_fp16[u][:]
// SHUFFLE-FREE layout (round-6 bottleneck was 24 ds_bpermute/node on the
// single LDS pipe): lane = (node-half, column-word). A wave covers 2 nodes;
// each half-wave's 32 lanes own the 32 u32 words (64 fp16 cols) of its
// node's row. Edge-row loads are half-wave-coalesced 128 B; each lane
// accumulates its own 2 columns -> no cross-lane reduce at all.
// src loads (same-address broadcast per half) are pipelined one batch ahead.
// ---------------------------------------------------------------------------
__global__ __launch_bounds__(256) void k_aggr(const __half* __restrict__ y,
                                              const int* __restrict__ src,
                                              const int* __restrict__ row_ptr,
                                              float* __restrict__ out) {
    const int lane = threadIdx.x & 63;
    const int half = lane >> 5;          // which of the wave's 2 nodes
    const int w    = lane & 31;          // u32 word within the 128 B row
    const int wid  = blockIdx.x * 4 + (threadIdx.x >> 6);
    const int v    = wid * 2 + half;     // 12500 blocks * 4 waves * 2 = NN
    if (v >= NN) return;

    const int lo = row_ptr[v];
    const int hi = row_ptr[v + 1];
    const int deg = hi - lo;

    float a0 = 0.0f, a1 = 0.0f;
    if (deg > 0) {
        const int last = hi - 1;
        int sv[4];
        #pragma unroll
        for (int u = 0; u < 4; ++u) sv[u] = src[min(lo + u, last)];
        for (int e = lo; e < hi; e += 4) {
            unsigned r[4];
            #pragma unroll
            for (int u = 0; u < 4; ++u)
                r[u] = *(const unsigned*)(y + (size_t)sv[u] * D + w * 2);
            const int en = e + 4;
            #pragma unroll
            for (int u = 0; u < 4; ++u) sv[u] = src[min(en + u, last)]; // prefetch
            #pragma unroll
            for (int u = 0; u < 4; ++u) {
                if (e + u < hi) {
                    const float2 f = cvt2(r[u]);
                    a0 += f.x; a1 += f.y;
                }
            }
        }
    }
    const float inv = (deg > 0) ? 1.0f / (float)deg : 0.0f;
    float2* op = (float2*)(out + (size_t)v * D + w * 2);  // 32 lanes = 256 B
    float2 o = *op;                                        // z from k_gemm
    o.x += a0 * inv;
    o.y += a1 * inv;
    *op = o;
}

extern "C" void kernel_launch(void* const* d_in, const int* in_sizes, int n_in,
                              void* d_out, int out_size, void* d_ws, size_t ws_size,
                              hipStream_t stream) {
    const float* x      = (const float*)d_in[0];
    const float* Wself  = (const float*)d_in[1];
    const float* Wneigh = (const float*)d_in[2];
    const float* b      = (const float*)d_in[3];
    const int*   src    = (const int*)d_in[4];
    const int*   dst    = (const int*)d_in[5];
    float* out = (float*)d_out;

    __half* y      = (__half*)d_ws;                            // [NN * D] fp16
    int*   row_ptr = (int*)((char*)d_ws + (size_t)NN * D * 2); // [NN + 1]

    k_rowptr<<<(NE + 255) / 256, 256, 0, stream>>>(dst, row_ptr);
    k_gemm<<<(NWID + 3) / 4, 256, 0, stream>>>(x, Wself, Wneigh, b, out, y);
    // 2 nodes per wave, 4 waves per block -> 12500 blocks covers NN exactly
    k_aggr<<<(NN + 7) / 8, 256, 0, stream>>>(y, src, row_ptr, out);
}

// Round 8
// 139.033 us; speedup vs baseline: 1.4049x; 1.1137x over previous
//
#include <hip/hip_runtime.h>
#include <hip/hip_fp16.h>

#define NN 100000
#define NE 1250000
#define D 64
#define MT 6250                 // NN / 16 M-tiles (exact, no tail)
#define RP_BLOCKS 4883          // ceil(NE/256) blocks for rowptr part of k_prep

typedef _Float16 h8 __attribute__((ext_vector_type(8)));
typedef float f4 __attribute__((ext_vector_type(4)));

__device__ inline float2 cvt2(unsigned u) {
    __half2 h = __builtin_bit_cast(__half2, u);
    return __half22float2(h);
}

// ---------------------------------------------------------------------------
// k_prep: blocks [0, RP_BLOCKS) build row_ptr from sorted dst.
// Blocks [RP_BLOCKS, RP_BLOCKS+64) pack W_self|W_neigh into per-lane MFMA
// B-fragments, split into fp16 hi + fp16 residual (lo):
//   element (t,f,l,i):  k = f*32 + (l>>4)*8 + i,  c = (t&3)*16 + (l&15)
//   value from Ws if t<4 else Wn; hi at Wp[r], lo at Wp[8192 + r],
//   r = ((t*2+f)*64 + l)*8 + i.  (B layout: col=lane&15, k=(lane>>4)*8+i)
// ---------------------------------------------------------------------------
__global__ __launch_bounds__(256) void k_prep(const int* __restrict__ dst,
                                              int* __restrict__ row_ptr,
                                              const float* __restrict__ Ws,
                                              const float* __restrict__ Wn,
                                              __half* __restrict__ Wp) {
    if (blockIdx.x < RP_BLOCKS) {
        const int i = blockIdx.x * 256 + threadIdx.x;
        if (i >= NE) return;
        const int d = dst[i];
        const int prev = (i == 0) ? -1 : dst[i - 1];
        for (int v = prev + 1; v <= d; ++v) row_ptr[v] = i;
        if (i == NE - 1) {
            for (int v = d + 1; v <= NN; ++v) row_ptr[v] = NE;
        }
    } else {
        const int id = (blockIdx.x - RP_BLOCKS) * 256 + threadIdx.x; // 0..16383
        const int p = id >> 13;        // 0 = hi, 1 = lo
        const int r = id & 8191;
        const int i = r & 7;
        const int l = (r >> 3) & 63;
        const int f = (r >> 9) & 1;
        const int t = r >> 10;         // 0..7
        const int k = f * 32 + ((l >> 4) * 8) + i;
        const int c = (t & 3) * 16 + (l & 15);
        const float v = ((t < 4) ? Ws : Wn)[k * D + c];
        const _Float16 hi = (_Float16)v;
        const _Float16 out = p ? (_Float16)(v - (float)hi) : hi;
        Wp[p * 8192 + r] = __builtin_bit_cast(__half, out);
    }
}

// ---------------------------------------------------------------------------
// k_mm: split-fp16 MFMA GEMM computing BOTH outputs in one x pass:
//   z[:, 0:64]  = x@Wself + b  -> d_out (fp32)
//   y[:, 0:64]  = x@Wneigh     -> ws (fp16, for the gather kernel)
// One wave per 16-row M-tile; iterates the 8 N-tiles (4 Ws + 4 Wn).
// A-frag: row = lane&15, k = (lane>>4)*8 + i. x loaded fp32 (16 floats/lane),
// split into hi+residual fp16 frags. acc = Al*Bh + Ah*Bl + Ah*Bh (fp32
// accumulate): GEMM error ~2^-21 — NO precision regression vs VALU fp32.
// C/D: col = lane&15, row = (lane>>4)*4 + reg.
// ---------------------------------------------------------------------------
__global__ __launch_bounds__(256) void k_mm(const float* __restrict__ x,
                                            const __half* __restrict__ Wp,
                                            const float* __restrict__ b,
                                            float* __restrict__ z,
                                            __half* __restrict__ y) {
    const int lane = threadIdx.x & 63;
    const int mt = blockIdx.x * 4 + (threadIdx.x >> 6);
    if (mt >= MT) return;
    const int row = lane & 15;
    const int kg = lane >> 4;               // 0..3
    const float* __restrict__ xr = x + (size_t)(mt * 16 + row) * D + kg * 8;

    const float4 v0 = *(const float4*)(xr);        // k = kg*8 + 0..3
    const float4 v1 = *(const float4*)(xr + 4);    // k = kg*8 + 4..7
    const float4 v2 = *(const float4*)(xr + 32);   // k = 32 + kg*8 + 0..3
    const float4 v3 = *(const float4*)(xr + 36);

    const float xf0[8] = {v0.x, v0.y, v0.z, v0.w, v1.x, v1.y, v1.z, v1.w};
    const float xf1[8] = {v2.x, v2.y, v2.z, v2.w, v3.x, v3.y, v3.z, v3.w};
    h8 ah0, al0, ah1, al1;
    #pragma unroll
    for (int i = 0; i < 8; ++i) {
        const _Float16 h0 = (_Float16)xf0[i];
        ah0[i] = h0;
        al0[i] = (_Float16)(xf0[i] - (float)h0);
        const _Float16 h1 = (_Float16)xf1[i];
        ah1[i] = h1;
        al1[i] = (_Float16)(xf1[i] - (float)h1);
    }

    const _Float16* __restrict__ wp = (const _Float16*)Wp;
    #pragma unroll
    for (int t = 0; t < 8; ++t) {
        const h8 bh0 = *(const h8*)(wp + ((t * 2 + 0) * 64 + lane) * 8);
        const h8 bh1 = *(const h8*)(wp + ((t * 2 + 1) * 64 + lane) * 8);
        const h8 bl0 = *(const h8*)(wp + 8192 + ((t * 2 + 0) * 64 + lane) * 8);
        const h8 bl1 = *(const h8*)(wp + 8192 + ((t * 2 + 1) * 64 + lane) * 8);
        f4 acc = {0.f, 0.f, 0.f, 0.f};
        // low-order terms first, then hi*hi
        acc = __builtin_amdgcn_mfma_f32_16x16x32_f16(al0, bh0, acc, 0, 0, 0);
        acc = __builtin_amdgcn_mfma_f32_16x16x32_f16(al1, bh1, acc, 0, 0, 0);
        acc = __builtin_amdgcn_mfma_f32_16x16x32_f16(ah0, bl0, acc, 0, 0, 0);
        acc = __builtin_amdgcn_mfma_f32_16x16x32_f16(ah1, bl1, acc, 0, 0, 0);
        acc = __builtin_amdgcn_mfma_f32_16x16x32_f16(ah0, bh0, acc, 0, 0, 0);
        acc = __builtin_amdgcn_mfma_f32_16x16x32_f16(ah1, bh1, acc, 0, 0, 0);

        const int col = (t & 3) * 16 + (lane & 15);
        const int r0 = mt * 16 + kg * 4;
        if (t < 4) {
            const float bb = b[col];
            #pragma unroll
            for (int reg = 0; reg < 4; ++reg)
                z[(size_t)(r0 + reg) * D + col] = acc[reg] + bb;
        } else {
            #pragma unroll
            for (int reg = 0; reg < 4; ++reg)
                y[(size_t)(r0 + reg) * D + col] = __float2half(acc[reg]);
        }
    }
}

// ---------------------------------------------------------------------------
// k_aggr: out[v][:] = z[v][:] + mean_{u in N(v)} y_fp16[u][:]
// Shuffle-free: lane = (node-half, column-word). Wave covers 2 nodes; each
// half-wave's 32 lanes own the 32 u32 words (64 fp16 cols) of its node's
// 128 B row. Edge-row loads are half-wave-coalesced; per-lane private
// accumulation; src loads pipelined one batch ahead. (unchanged, round 7)
// ---------------------------------------------------------------------------
__global__ __launch_bounds__(256) void k_aggr(const __half* __restrict__ y,
                                              const int* __restrict__ src,
                                              const int* __restrict__ row_ptr,
                                              float* __restrict__ out) {
    const int lane = threadIdx.x & 63;
    const int half = lane >> 5;
    const int w    = lane & 31;
    const int wid  = blockIdx.x * 4 + (threadIdx.x >> 6);
    const int v    = wid * 2 + half;
    if (v >= NN) return;

    const int lo = row_ptr[v];
    const int hi = row_ptr[v + 1];
    const int deg = hi - lo;

    float a0 = 0.0f, a1 = 0.0f;
    if (deg > 0) {
        const int last = hi - 1;
        int sv[4];
        #pragma unroll
        for (int u = 0; u < 4; ++u) sv[u] = src[min(lo + u, last)];
        for (int e = lo; e < hi; e += 4) {
            unsigned r[4];
            #pragma unroll
            for (int u = 0; u < 4; ++u)
                r[u] = *(const unsigned*)(y + (size_t)sv[u] * D + w * 2);
            const int en = e + 4;
            #pragma unroll
            for (int u = 0; u < 4; ++u) sv[u] = src[min(en + u, last)];
            #pragma unroll
            for (int u = 0; u < 4; ++u) {
                if (e + u < hi) {
                    const float2 f = cvt2(r[u]);
                    a0 += f.x; a1 += f.y;
                }
            }
        }
    }
    const float inv = (deg > 0) ? 1.0f / (float)deg : 0.0f;
    float2* op = (float2*)(out + (size_t)v * D + w * 2);
    float2 o = *op;     // z from k_mm
    o.x += a0 * inv;
    o.y += a1 * inv;
    *op = o;
}

extern "C" void kernel_launch(void* const* d_in, const int* in_sizes, int n_in,
                              void* d_out, int out_size, void* d_ws, size_t ws_size,
                              hipStream_t stream) {
    const float* x      = (const float*)d_in[0];
    const float* Wself  = (const float*)d_in[1];
    const float* Wneigh = (const float*)d_in[2];
    const float* b      = (const float*)d_in[3];
    const int*   src    = (const int*)d_in[4];
    const int*   dst    = (const int*)d_in[5];
    float* out = (float*)d_out;

    // ws layout (16 B aligned blocks): y fp16 | row_ptr | Wp (hi 8192 + lo 8192)
    __half* y = (__half*)d_ws;
    const size_t yb = (size_t)NN * D * 2;                       // 12,800,000
    int* row_ptr = (int*)((char*)d_ws + yb);
    const size_t rpb = (((size_t)(NN + 1) * 4) + 15) & ~(size_t)15;
    __half* Wp = (__half*)((char*)d_ws + yb + rpb);

    k_prep<<<RP_BLOCKS + 64, 256, 0, stream>>>(dst, row_ptr, Wself, Wneigh, Wp);
    k_mm<<<(MT + 3) / 4, 256, 0, stream>>>(x, Wp, b, out, y);
    k_aggr<<<(NN + 7) / 8, 256, 0, stream>>>(y, src, row_ptr, out);
}

// Round 9
// 133.048 us; speedup vs baseline: 1.4681x; 1.0450x over previous
//
#include <hip/hip_runtime.h>
#include <hip/hip_fp16.h>

#define NN 100000
#define NE 1250000
#define D 64
#define MT 6250                 // NN / 16 M-tiles (exact, no tail)
#define RP_BLOCKS 4883          // ceil(NE/256) blocks for rowptr part of k_prep
#define ANB 8                   // aggr nodes per block (4 waves x 2)
#define MAXLE 2048              // LDS edge cache (8 KB); block mean ~100 edges

typedef _Float16 h8 __attribute__((ext_vector_type(8)));
typedef float f4 __attribute__((ext_vector_type(4)));

__device__ inline float2 cvt2(unsigned u) {
    __half2 h = __builtin_bit_cast(__half2, u);
    return __half22float2(h);
}

// ---------------------------------------------------------------------------
// k_prep: blocks [0, RP_BLOCKS) build row_ptr from sorted dst.
// Blocks [RP_BLOCKS, RP_BLOCKS+64) pack W_self|W_neigh into per-lane MFMA
// B-fragments split into fp16 hi + fp16 residual (lo). (unchanged, round 8)
// ---------------------------------------------------------------------------
__global__ __launch_bounds__(256) void k_prep(const int* __restrict__ dst,
                                              int* __restrict__ row_ptr,
                                              const float* __restrict__ Ws,
                                              const float* __restrict__ Wn,
                                              __half* __restrict__ Wp) {
    if (blockIdx.x < RP_BLOCKS) {
        const int i = blockIdx.x * 256 + threadIdx.x;
        if (i >= NE) return;
        const int d = dst[i];
        const int prev = (i == 0) ? -1 : dst[i - 1];
        for (int v = prev + 1; v <= d; ++v) row_ptr[v] = i;
        if (i == NE - 1) {
            for (int v = d + 1; v <= NN; ++v) row_ptr[v] = NE;
        }
    } else {
        const int id = (blockIdx.x - RP_BLOCKS) * 256 + threadIdx.x; // 0..16383
        const int p = id >> 13;        // 0 = hi, 1 = lo
        const int r = id & 8191;
        const int i = r & 7;
        const int l = (r >> 3) & 63;
        const int f = (r >> 9) & 1;
        const int t = r >> 10;         // 0..7
        const int k = f * 32 + ((l >> 4) * 8) + i;
        const int c = (t & 3) * 16 + (l & 15);
        const float v = ((t < 4) ? Ws : Wn)[k * D + c];
        const _Float16 hi = (_Float16)v;
        const _Float16 out = p ? (_Float16)(v - (float)hi) : hi;
        Wp[p * 8192 + r] = __builtin_bit_cast(__half, out);
    }
}

// ---------------------------------------------------------------------------
// k_mm: split-fp16 MFMA GEMM, one x pass -> z (d_out, fp32) and y (ws, fp16).
// acc = Al*Bh + Ah*Bl + Ah*Bh, fp32 accumulate: error ~2^-21. (unchanged)
// ---------------------------------------------------------------------------
__global__ __launch_bounds__(256) void k_mm(const float* __restrict__ x,
                                            const __half* __restrict__ Wp,
                                            const float* __restrict__ b,
                                            float* __restrict__ z,
                                            __half* __restrict__ y) {
    const int lane = threadIdx.x & 63;
    const int mt = blockIdx.x * 4 + (threadIdx.x >> 6);
    if (mt >= MT) return;
    const int row = lane & 15;
    const int kg = lane >> 4;               // 0..3
    const float* __restrict__ xr = x + (size_t)(mt * 16 + row) * D + kg * 8;

    const float4 v0 = *(const float4*)(xr);
    const float4 v1 = *(const float4*)(xr + 4);
    const float4 v2 = *(const float4*)(xr + 32);
    const float4 v3 = *(const float4*)(xr + 36);

    const float xf0[8] = {v0.x, v0.y, v0.z, v0.w, v1.x, v1.y, v1.z, v1.w};
    const float xf1[8] = {v2.x, v2.y, v2.z, v2.w, v3.x, v3.y, v3.z, v3.w};
    h8 ah0, al0, ah1, al1;
    #pragma unroll
    for (int i = 0; i < 8; ++i) {
        const _Float16 h0 = (_Float16)xf0[i];
        ah0[i] = h0;
        al0[i] = (_Float16)(xf0[i] - (float)h0);
        const _Float16 h1 = (_Float16)xf1[i];
        ah1[i] = h1;
        al1[i] = (_Float16)(xf1[i] - (float)h1);
    }

    const _Float16* __restrict__ wp = (const _Float16*)Wp;
    #pragma unroll
    for (int t = 0; t < 8; ++t) {
        const h8 bh0 = *(const h8*)(wp + ((t * 2 + 0) * 64 + lane) * 8);
        const h8 bh1 = *(const h8*)(wp + ((t * 2 + 1) * 64 + lane) * 8);
        const h8 bl0 = *(const h8*)(wp + 8192 + ((t * 2 + 0) * 64 + lane) * 8);
        const h8 bl1 = *(const h8*)(wp + 8192 + ((t * 2 + 1) * 64 + lane) * 8);
        f4 acc = {0.f, 0.f, 0.f, 0.f};
        acc = __builtin_amdgcn_mfma_f32_16x16x32_f16(al0, bh0, acc, 0, 0, 0);
        acc = __builtin_amdgcn_mfma_f32_16x16x32_f16(al1, bh1, acc, 0, 0, 0);
        acc = __builtin_amdgcn_mfma_f32_16x16x32_f16(ah0, bl0, acc, 0, 0, 0);
        acc = __builtin_amdgcn_mfma_f32_16x16x32_f16(ah1, bl1, acc, 0, 0, 0);
        acc = __builtin_amdgcn_mfma_f32_16x16x32_f16(ah0, bh0, acc, 0, 0, 0);
        acc = __builtin_amdgcn_mfma_f32_16x16x32_f16(ah1, bh1, acc, 0, 0, 0);

        const int col = (t & 3) * 16 + (lane & 15);
        const int r0 = mt * 16 + kg * 4;
        if (t < 4) {
            const float bb = b[col];
            #pragma unroll
            for (int reg = 0; reg < 4; ++reg)
                z[(size_t)(r0 + reg) * D + col] = acc[reg] + bb;
        } else {
            #pragma unroll
            for (int reg = 0; reg < 4; ++reg)
                y[(size_t)(r0 + reg) * D + col] = __float2half(acc[reg]);
        }
    }
}

// ---------------------------------------------------------------------------
// k_aggr v4: out[v][:] = z[v][:] + mean_{u in N(v)} y_fp16[u][:]
// Round 6->7 showed shuffles were NOT the bottleneck; the gather fill path
// (78 MB per-XCD compulsory, ~2.3 TB/s) is. Hypothesis (b): src prefetch
// loads share the vmcnt counter with the gathers, serializing batches.
// Fix: stage the block's whole edge list in LDS (ds_read = lgkmcnt, a
// separate counter), so 8 gather rows per half-wave issue back-to-back.
// Layout unchanged: wave = 2 nodes, half-wave's 32 lanes own the 32 u32
// words of its node's 128 B fp16 row; per-lane private accumulation.
// ---------------------------------------------------------------------------
__global__ __launch_bounds__(256) void k_aggr(const __half* __restrict__ y,
                                              const int* __restrict__ src,
                                              const int* __restrict__ row_ptr,
                                              float* __restrict__ out) {
    __shared__ int s_src[MAXLE];
    __shared__ int s_rp[ANB + 1];
    const int tid = threadIdx.x;
    const int v0 = blockIdx.x * ANB;          // 12500 blocks * 8 = NN exactly

    if (tid <= ANB) s_rp[tid] = row_ptr[v0 + tid];
    __syncthreads();
    const int base = s_rp[0];
    const int cnt = s_rp[ANB] - base;
    const bool fits = (cnt <= MAXLE);         // mean 100, 2048 is >90 sigma
    if (fits) {
        for (int i = tid; i < cnt; i += 256) s_src[i] = src[base + i];
    }
    __syncthreads();

    const int lane = tid & 63;
    const int half = lane >> 5;
    const int w    = lane & 31;
    const int node = (tid >> 6) * 2 + half;   // 0..7 within block
    const int v    = v0 + node;
    const int lo = s_rp[node];
    const int hi = s_rp[node + 1];
    const int deg = hi - lo;

    float a0 = 0.0f, a1 = 0.0f;
    if (deg > 0) {
        const int last = hi - 1;
        if (fits) {
            for (int e = lo; e < hi; e += 8) {
                int sv[8];
                #pragma unroll
                for (int u = 0; u < 8; ++u)
                    sv[u] = s_src[min(e + u, last) - base];     // lgkmcnt only
                unsigned r[8];
                #pragma unroll
                for (int u = 0; u < 8; ++u)                      // 8 rows in flight
                    r[u] = *(const unsigned*)(y + (size_t)sv[u] * D + w * 2);
                #pragma unroll
                for (int u = 0; u < 8; ++u) {
                    if (e + u < hi) {
                        const float2 f = cvt2(r[u]);
                        a0 += f.x; a1 += f.y;
                    }
                }
            }
        } else {  // correctness fallback (practically never taken)
            for (int e = lo; e < hi; e += 8) {
                int sv[8];
                #pragma unroll
                for (int u = 0; u < 8; ++u) sv[u] = src[min(e + u, last)];
                unsigned r[8];
                #pragma unroll
                for (int u = 0; u < 8; ++u)
                    r[u] = *(const unsigned*)(y + (size_t)sv[u] * D + w * 2);
                #pragma unroll
                for (int u = 0; u < 8; ++u) {
                    if (e + u < hi) {
                        const float2 f = cvt2(r[u]);
                        a0 += f.x; a1 += f.y;
                    }
                }
            }
        }
    }
    const float inv = (deg > 0) ? 1.0f / (float)deg : 0.0f;
    float2* op = (float2*)(out + (size_t)v * D + w * 2);  // 32 lanes = 256 B
    float2 o = *op;                                        // z from k_mm
    o.x += a0 * inv;
    o.y += a1 * inv;
    *op = o;
}

extern "C" void kernel_launch(void* const* d_in, const int* in_sizes, int n_in,
                              void* d_out, int out_size, void* d_ws, size_t ws_size,
                              hipStream_t stream) {
    const float* x      = (const float*)d_in[0];
    const float* Wself  = (const float*)d_in[1];
    const float* Wneigh = (const float*)d_in[2];
    const float* b      = (const float*)d_in[3];
    const int*   src    = (const int*)d_in[4];
    const int*   dst    = (const int*)d_in[5];
    float* out = (float*)d_out;

    // ws layout: y fp16 | row_ptr | Wp (hi 8192 + lo 8192 halves)
    __half* y = (__half*)d_ws;
    const size_t yb = (size_t)NN * D * 2;
    int* row_ptr = (int*)((char*)d_ws + yb);
    const size_t rpb = (((size_t)(NN + 1) * 4) + 15) & ~(size_t)15;
    __half* Wp = (__half*)((char*)d_ws + yb + rpb);

    k_prep<<<RP_BLOCKS + 64, 256, 0, stream>>>(dst, row_ptr, Wself, Wneigh, Wp);
    k_mm<<<(MT + 3) / 4, 256, 0, stream>>>(x, Wp, b, out, y);
    k_aggr<<<NN / ANB, 256, 0, stream>>>(y, src, row_ptr, out);
}